// Round 1
// baseline (3527.390 us; speedup 1.0000x reference)
//
#include <hip/hip_runtime.h>

#define N_NODES   50000
#define N_EDGES   600000
#define F         128
#define N_GRAPHS  64
#define N_CLASSES 10

// ---------------- edge scatter-add (atomic) ----------------
// 32 threads per edge, float4 per thread: gather x[src], atomic-add into agg[dst]
__global__ __launch_bounds__(256) void scatter_kernel(
    const float* __restrict__ X, const int* __restrict__ src,
    const int* __restrict__ dst, float* __restrict__ agg)
{
    int gid = blockIdx.x * 256 + threadIdx.x;
    int e  = gid >> 5;
    int f4 = (gid & 31) << 2;
    if (e >= N_EDGES) return;
    int s = src[e];
    int d = dst[e];
    const float4 v = *reinterpret_cast<const float4*>(X + (size_t)s * F + f4);
    float* p = agg + (size_t)d * F + f4;
    unsafeAtomicAdd(p + 0, v.x);
    unsafeAtomicAdd(p + 1, v.y);
    unsafeAtomicAdd(p + 2, v.z);
    unsafeAtomicAdd(p + 3, v.w);
}

// ---------------- fused GraphConv: h = [relu](agg@Wrel^T + b + x@Wroot^T) ----------------
// 64-row tile per block, 256 threads, 8x4 micro-tile per thread.
template <int RELU>
__global__ __launch_bounds__(256) void conv_kernel(
    const float* __restrict__ AGG, const float* __restrict__ X,
    const float* __restrict__ Wrel, const float* __restrict__ brel,
    const float* __restrict__ Wroot, float* __restrict__ H, int nRows)
{
    __shared__ float As[64][F];
    __shared__ float Xs[64][F];
    __shared__ float Ws[16][F];   // K-slice of weights, transposed: Ws[k2][o]

    const int t = threadIdx.x;
    const int rowBase = blockIdx.x * 64;

    // stage A and X tiles (coalesced float4, conflict-free LDS writes)
    for (int i = 0; i < 8; ++i) {
        int idx = i * 256 + t;        // float4 index 0..2047
        int r   = idx >> 5;
        int c4  = (idx & 31) << 2;
        int row = rowBase + r;
        float4 va, vx;
        if (row < nRows) {
            va = *reinterpret_cast<const float4*>(AGG + (size_t)row * F + c4);
            vx = *reinterpret_cast<const float4*>(X   + (size_t)row * F + c4);
        } else {
            va = make_float4(0.f, 0.f, 0.f, 0.f);
            vx = va;
        }
        *reinterpret_cast<float4*>(&As[r][c4]) = va;
        *reinterpret_cast<float4*>(&Xs[r][c4]) = vx;
    }

    const int cg = t & 31;
    const int rg = t >> 5;
    const int c0 = cg << 2;   // 4 consecutive output cols
    const int r0 = rg << 3;   // 8 consecutive rows

    float acc[8][4];
#pragma unroll
    for (int i = 0; i < 8; ++i)
#pragma unroll
        for (int j = 0; j < 4; ++j) acc[i][j] = 0.f;

#define PHASE(SARR, WG)                                                          \
    for (int kk = 0; kk < 8; ++kk) {                                             \
        __syncthreads();                                                         \
        for (int li = 0; li < 8; ++li) {                                         \
            int j  = li * 256 + t;                                               \
            int o  = j >> 4;                                                     \
            int k2 = j & 15;                                                     \
            Ws[k2][o] = WG[o * F + kk * 16 + k2];                                \
        }                                                                        \
        __syncthreads();                                                         \
        _Pragma("unroll")                                                        \
        for (int k2 = 0; k2 < 16; ++k2) {                                        \
            int k = kk * 16 + k2;                                                \
            float4 w = *reinterpret_cast<const float4*>(&Ws[k2][c0]);            \
            _Pragma("unroll")                                                    \
            for (int i = 0; i < 8; ++i) {                                        \
                float a = SARR[r0 + i][k];                                       \
                acc[i][0] += a * w.x;                                            \
                acc[i][1] += a * w.y;                                            \
                acc[i][2] += a * w.z;                                            \
                acc[i][3] += a * w.w;                                            \
            }                                                                    \
        }                                                                        \
    }

    PHASE(As, Wrel)
    PHASE(Xs, Wroot)
#undef PHASE

    const float4 bb = *reinterpret_cast<const float4*>(brel + c0);
#pragma unroll
    for (int i = 0; i < 8; ++i) {
        int row = rowBase + r0 + i;
        if (row < nRows) {
            float4 o;
            o.x = acc[i][0] + bb.x;
            o.y = acc[i][1] + bb.y;
            o.z = acc[i][2] + bb.z;
            o.w = acc[i][3] + bb.w;
            if (RELU) {
                o.x = fmaxf(o.x, 0.f); o.y = fmaxf(o.y, 0.f);
                o.z = fmaxf(o.z, 0.f); o.w = fmaxf(o.w, 0.f);
            }
            *reinterpret_cast<float4*>(H + (size_t)row * F + c0) = o;
        }
    }
}

// ---------------- mean pool per graph (batch sorted -> binary search bounds) ----------------
__global__ __launch_bounds__(256) void pool_kernel(
    const float* __restrict__ H, const int* __restrict__ batch,
    float* __restrict__ G)
{
    int g = blockIdx.x;
    int lo = 0, hi = N_NODES;
    while (lo < hi) { int m = (lo + hi) >> 1; if (batch[m] < g) lo = m + 1; else hi = m; }
    int start = lo;
    hi = N_NODES;
    while (lo < hi) { int m = (lo + hi) >> 1; if (batch[m] < g + 1) lo = m + 1; else hi = m; }
    int end = lo;

    int f   = threadIdx.x & 127;
    int sub = threadIdx.x >> 7;   // 0/1
    float s = 0.f;
    for (int i = start + sub; i < end; i += 2)
        s += H[(size_t)i * F + f];

    __shared__ float part[2][F];
    part[sub][f] = s;
    __syncthreads();
    if (threadIdx.x < F) {
        float cnt = (float)(end - start);
        G[g * F + f] = (part[0][f] + part[1][f]) / fmaxf(cnt, 1.f);
    }
}

// ---------------- classifier head: out = G @ Wl^T + bl ----------------
__global__ __launch_bounds__(640) void head_kernel(
    const float* __restrict__ G, const float* __restrict__ Wl,
    const float* __restrict__ bl, float* __restrict__ out)
{
    int t = threadIdx.x;           // 0..639
    int g = t / N_CLASSES;
    int c = t % N_CLASSES;
    float s = bl[c];
#pragma unroll 8
    for (int k = 0; k < F; ++k) s += G[g * F + k] * Wl[c * F + k];
    out[t] = s;
}

extern "C" void kernel_launch(void* const* d_in, const int* in_sizes, int n_in,
                              void* d_out, int out_size, void* d_ws, size_t ws_size,
                              hipStream_t stream)
{
    const float* x     = (const float*)d_in[0];
    const int*   edge  = (const int*)d_in[1];      // [2][E]
    const int*   src   = edge;
    const int*   dst   = edge + N_EDGES;
    const int*   batch = (const int*)d_in[2];
    const float* W1r = (const float*)d_in[3];
    const float* b1  = (const float*)d_in[4];
    const float* W1o = (const float*)d_in[5];
    const float* W2r = (const float*)d_in[6];
    const float* b2  = (const float*)d_in[7];
    const float* W2o = (const float*)d_in[8];
    const float* W3r = (const float*)d_in[9];
    const float* b3  = (const float*)d_in[10];
    const float* W3o = (const float*)d_in[11];
    const float* Wl  = (const float*)d_in[12];
    const float* bl  = (const float*)d_in[13];
    float* out = (float*)d_out;

    char* ws = (char*)d_ws;
    const size_t nb = (size_t)N_NODES * F * sizeof(float);   // 25.6 MB
    float* AGG = (float*)ws;
    float* H1  = (float*)(ws + nb);
    float* H2  = (float*)(ws + 2 * nb);
    float* G   = (float*)(ws + 3 * nb);

    const int scatterBlocks = (N_EDGES * 32) / 256;          // 75000
    const int convBlocks    = (N_NODES + 63) / 64;           // 782

    // layer 1
    hipMemsetAsync(AGG, 0, nb, stream);
    scatter_kernel<<<scatterBlocks, 256, 0, stream>>>(x, src, dst, AGG);
    conv_kernel<1><<<convBlocks, 256, 0, stream>>>(AGG, x, W1r, b1, W1o, H1, N_NODES);
    // layer 2
    hipMemsetAsync(AGG, 0, nb, stream);
    scatter_kernel<<<scatterBlocks, 256, 0, stream>>>(H1, src, dst, AGG);
    conv_kernel<1><<<convBlocks, 256, 0, stream>>>(AGG, H1, W2r, b2, W2o, H2, N_NODES);
    // layer 3
    hipMemsetAsync(AGG, 0, nb, stream);
    scatter_kernel<<<scatterBlocks, 256, 0, stream>>>(H2, src, dst, AGG);
    conv_kernel<0><<<convBlocks, 256, 0, stream>>>(AGG, H2, W3r, b3, W3o, H1, N_NODES);
    // pool + head
    pool_kernel<<<N_GRAPHS, 256, 0, stream>>>(H1, batch, G);
    head_kernel<<<1, 640, 0, stream>>>(G, Wl, bl, out);
}

// Round 2
// 767.337 us; speedup vs baseline: 4.5969x; 4.5969x over previous
//
#include <hip/hip_runtime.h>

#define N_NODES   50000
#define N_EDGES   600000
#define F         128
#define N_GRAPHS  64
#define N_CLASSES 10

// ================= CSR build =================
__global__ __launch_bounds__(256) void hist_kernel(
    const int* __restrict__ dst, int* __restrict__ deg)
{
    int e = blockIdx.x * 256 + threadIdx.x;
    if (e >= N_EDGES) return;
    atomicAdd(&deg[dst[e]], 1);
}

// single-block exclusive scan of deg[50000] -> off[50001]
__global__ __launch_bounds__(1024) void scan_kernel(
    const int* __restrict__ deg, int* __restrict__ off)
{
    __shared__ int part[1024];
    const int t = threadIdx.x;
    const int CH = (N_NODES + 1023) / 1024;   // 49
    const int base = t * CH;
    int s = 0;
    for (int i = 0; i < CH; ++i) {
        int idx = base + i;
        if (idx < N_NODES) s += deg[idx];
    }
    part[t] = s;
    __syncthreads();
    for (int d = 1; d < 1024; d <<= 1) {
        int v = (t >= d) ? part[t - d] : 0;
        __syncthreads();
        part[t] += v;
        __syncthreads();
    }
    int run = (t == 0) ? 0 : part[t - 1];
    for (int i = 0; i < CH; ++i) {
        int idx = base + i;
        if (idx < N_NODES) {
            off[idx] = run;
            run += deg[idx];
        }
    }
    if (t == 1023) off[N_NODES] = part[1023];
}

__global__ __launch_bounds__(256) void fill_kernel(
    const int* __restrict__ src, const int* __restrict__ dst,
    const int* __restrict__ off, int* __restrict__ cursor,
    int* __restrict__ csr_src)
{
    int e = blockIdx.x * 256 + threadIdx.x;
    if (e >= N_EDGES) return;
    int d = dst[e];
    int slot = atomicAdd(&cursor[d], 1);
    csr_src[off[d] + slot] = src[e];
}

// ================= gather aggregation (no atomics, no memset needed) =================
// 32 threads per node, float4 per thread
__global__ __launch_bounds__(256) void gather_kernel(
    const float* __restrict__ X, const int* __restrict__ off,
    const int* __restrict__ csr_src, float* __restrict__ agg)
{
    int gid  = blockIdx.x * 256 + threadIdx.x;
    int node = gid >> 5;
    int f4   = (gid & 31) << 2;
    if (node >= N_NODES) return;
    int s0 = off[node], s1 = off[node + 1];
    float4 acc = make_float4(0.f, 0.f, 0.f, 0.f);
    for (int j = s0; j < s1; ++j) {
        int s = csr_src[j];   // uniform across the 32-lane subgroup -> broadcast
        const float4 v = *reinterpret_cast<const float4*>(X + (size_t)s * F + f4);
        acc.x += v.x; acc.y += v.y; acc.z += v.z; acc.w += v.w;
    }
    *reinterpret_cast<float4*>(agg + (size_t)node * F + f4) = acc;
}

// ================= fused GraphConv: h = [relu](agg@Wrel^T + b + x@Wroot^T) =================
template <int RELU>
__global__ __launch_bounds__(256) void conv_kernel(
    const float* __restrict__ AGG, const float* __restrict__ X,
    const float* __restrict__ Wrel, const float* __restrict__ brel,
    const float* __restrict__ Wroot, float* __restrict__ H, int nRows)
{
    __shared__ float As[64][F];
    __shared__ float Xs[64][F];
    __shared__ float Ws[16][F];   // K-slice of weights, transposed: Ws[k2][o]

    const int t = threadIdx.x;
    const int rowBase = blockIdx.x * 64;

    for (int i = 0; i < 8; ++i) {
        int idx = i * 256 + t;
        int r   = idx >> 5;
        int c4  = (idx & 31) << 2;
        int row = rowBase + r;
        float4 va, vx;
        if (row < nRows) {
            va = *reinterpret_cast<const float4*>(AGG + (size_t)row * F + c4);
            vx = *reinterpret_cast<const float4*>(X   + (size_t)row * F + c4);
        } else {
            va = make_float4(0.f, 0.f, 0.f, 0.f);
            vx = va;
        }
        *reinterpret_cast<float4*>(&As[r][c4]) = va;
        *reinterpret_cast<float4*>(&Xs[r][c4]) = vx;
    }

    const int cg = t & 31;
    const int rg = t >> 5;
    const int c0 = cg << 2;
    const int r0 = rg << 3;

    float acc[8][4];
#pragma unroll
    for (int i = 0; i < 8; ++i)
#pragma unroll
        for (int j = 0; j < 4; ++j) acc[i][j] = 0.f;

#define PHASE(SARR, WG)                                                          \
    for (int kk = 0; kk < 8; ++kk) {                                             \
        __syncthreads();                                                         \
        for (int li = 0; li < 8; ++li) {                                         \
            int j  = li * 256 + t;                                               \
            int o  = j >> 4;                                                     \
            int k2 = j & 15;                                                     \
            Ws[k2][o] = WG[o * F + kk * 16 + k2];                                \
        }                                                                        \
        __syncthreads();                                                         \
        _Pragma("unroll")                                                        \
        for (int k2 = 0; k2 < 16; ++k2) {                                        \
            int k = kk * 16 + k2;                                                \
            float4 w = *reinterpret_cast<const float4*>(&Ws[k2][c0]);            \
            _Pragma("unroll")                                                    \
            for (int i = 0; i < 8; ++i) {                                        \
                float a = SARR[r0 + i][k];                                       \
                acc[i][0] += a * w.x;                                            \
                acc[i][1] += a * w.y;                                            \
                acc[i][2] += a * w.z;                                            \
                acc[i][3] += a * w.w;                                            \
            }                                                                    \
        }                                                                        \
    }

    PHASE(As, Wrel)
    PHASE(Xs, Wroot)
#undef PHASE

    const float4 bb = *reinterpret_cast<const float4*>(brel + c0);
#pragma unroll
    for (int i = 0; i < 8; ++i) {
        int row = rowBase + r0 + i;
        if (row < nRows) {
            float4 o;
            o.x = acc[i][0] + bb.x;
            o.y = acc[i][1] + bb.y;
            o.z = acc[i][2] + bb.z;
            o.w = acc[i][3] + bb.w;
            if (RELU) {
                o.x = fmaxf(o.x, 0.f); o.y = fmaxf(o.y, 0.f);
                o.z = fmaxf(o.z, 0.f); o.w = fmaxf(o.w, 0.f);
            }
            *reinterpret_cast<float4*>(H + (size_t)row * F + c0) = o;
        }
    }
}

// ================= mean pool =================
__global__ __launch_bounds__(256) void pool_kernel(
    const float* __restrict__ H, const int* __restrict__ batch,
    float* __restrict__ G)
{
    int g = blockIdx.x;
    int lo = 0, hi = N_NODES;
    while (lo < hi) { int m = (lo + hi) >> 1; if (batch[m] < g) lo = m + 1; else hi = m; }
    int start = lo;
    hi = N_NODES;
    while (lo < hi) { int m = (lo + hi) >> 1; if (batch[m] < g + 1) lo = m + 1; else hi = m; }
    int end = lo;

    int f   = threadIdx.x & 127;
    int sub = threadIdx.x >> 7;
    float s = 0.f;
    for (int i = start + sub; i < end; i += 2)
        s += H[(size_t)i * F + f];

    __shared__ float part[2][F];
    part[sub][f] = s;
    __syncthreads();
    if (threadIdx.x < F) {
        float cnt = (float)(end - start);
        G[g * F + f] = (part[0][f] + part[1][f]) / fmaxf(cnt, 1.f);
    }
}

// ================= head =================
__global__ __launch_bounds__(640) void head_kernel(
    const float* __restrict__ G, const float* __restrict__ Wl,
    const float* __restrict__ bl, float* __restrict__ out)
{
    int t = threadIdx.x;
    int g = t / N_CLASSES;
    int c = t % N_CLASSES;
    float s = bl[c];
#pragma unroll 8
    for (int k = 0; k < F; ++k) s += G[g * F + k] * Wl[c * F + k];
    out[t] = s;
}

extern "C" void kernel_launch(void* const* d_in, const int* in_sizes, int n_in,
                              void* d_out, int out_size, void* d_ws, size_t ws_size,
                              hipStream_t stream)
{
    const float* x     = (const float*)d_in[0];
    const int*   edge  = (const int*)d_in[1];
    const int*   src   = edge;
    const int*   dst   = edge + N_EDGES;
    const int*   batch = (const int*)d_in[2];
    const float* W1r = (const float*)d_in[3];
    const float* b1  = (const float*)d_in[4];
    const float* W1o = (const float*)d_in[5];
    const float* W2r = (const float*)d_in[6];
    const float* b2  = (const float*)d_in[7];
    const float* W2o = (const float*)d_in[8];
    const float* W3r = (const float*)d_in[9];
    const float* b3  = (const float*)d_in[10];
    const float* W3o = (const float*)d_in[11];
    const float* Wl  = (const float*)d_in[12];
    const float* bl  = (const float*)d_in[13];
    float* out = (float*)d_out;

    char* ws = (char*)d_ws;
    const size_t nb = (size_t)N_NODES * F * sizeof(float);   // 25.6 MB
    float* AGG = (float*)ws;
    float* H1  = (float*)(ws + nb);
    float* H2  = (float*)(ws + 2 * nb);
    float* G   = (float*)(ws + 3 * nb);
    char*  p   = ws + 3 * nb + 64 * F * sizeof(float);
    int* deg     = (int*)p;              p += (size_t)N_NODES * sizeof(int);
    int* cursor  = (int*)p;              p += (size_t)N_NODES * sizeof(int);
    int* off     = (int*)p;              p += (size_t)(N_NODES + 1) * sizeof(int);
    int* csr_src = (int*)p;

    const int edgeBlocks   = (N_EDGES + 255) / 256;          // 2344
    const int gatherBlocks = (N_NODES * 32) / 256;           // 6250
    const int convBlocks   = (N_NODES + 63) / 64;            // 782

    // ---- CSR build (once, reused by all 3 layers) ----
    hipMemsetAsync(deg, 0, (size_t)N_NODES * sizeof(int), stream);
    hipMemsetAsync(cursor, 0, (size_t)N_NODES * sizeof(int), stream);
    hist_kernel<<<edgeBlocks, 256, 0, stream>>>(dst, deg);
    scan_kernel<<<1, 1024, 0, stream>>>(deg, off);
    fill_kernel<<<edgeBlocks, 256, 0, stream>>>(src, dst, off, cursor, csr_src);

    // ---- layer 1 ----
    gather_kernel<<<gatherBlocks, 256, 0, stream>>>(x, off, csr_src, AGG);
    conv_kernel<1><<<convBlocks, 256, 0, stream>>>(AGG, x, W1r, b1, W1o, H1, N_NODES);
    // ---- layer 2 ----
    gather_kernel<<<gatherBlocks, 256, 0, stream>>>(H1, off, csr_src, AGG);
    conv_kernel<1><<<convBlocks, 256, 0, stream>>>(AGG, H1, W2r, b2, W2o, H2, N_NODES);
    // ---- layer 3 ----
    gather_kernel<<<gatherBlocks, 256, 0, stream>>>(H2, off, csr_src, AGG);
    conv_kernel<0><<<convBlocks, 256, 0, stream>>>(AGG, H2, W3r, b3, W3o, H1, N_NODES);
    // ---- pool + head ----
    pool_kernel<<<N_GRAPHS, 256, 0, stream>>>(H1, batch, G);
    head_kernel<<<1, 640, 0, stream>>>(G, Wl, bl, out);
}

// Round 3
// 389.806 us; speedup vs baseline: 9.0491x; 1.9685x over previous
//
#include <hip/hip_runtime.h>
#include <hip/hip_bf16.h>

#define N_NODES   50000
#define N_EDGES   600000
#define F         128
#define N_GRAPHS  64
#define N_CLASSES 10
#define NPAD      50048   // 782 * 64

typedef __attribute__((ext_vector_type(8))) short bf16x8;
typedef __attribute__((ext_vector_type(4))) float f32x4;

static __device__ __forceinline__ unsigned short f2bf(float f) {
    __hip_bfloat16 h = __float2bfloat16(f);
    return *reinterpret_cast<unsigned short*>(&h);
}
static __device__ __forceinline__ float bf2f(unsigned short u) {
    return __uint_as_float(((unsigned)u) << 16);
}

// ================= CSR build =================
__global__ __launch_bounds__(256) void hist_kernel(
    const int* __restrict__ dst, int* __restrict__ deg)
{
    int e = blockIdx.x * 256 + threadIdx.x;
    if (e >= N_EDGES) return;
    atomicAdd(&deg[dst[e]], 1);
}

__global__ __launch_bounds__(1024) void scan_kernel(
    const int* __restrict__ deg, int* __restrict__ off)
{
    __shared__ int part[1024];
    const int t = threadIdx.x;
    const int CH = (N_NODES + 1023) / 1024;
    const int base = t * CH;
    int s = 0;
    for (int i = 0; i < CH; ++i) {
        int idx = base + i;
        if (idx < N_NODES) s += deg[idx];
    }
    part[t] = s;
    __syncthreads();
    for (int d = 1; d < 1024; d <<= 1) {
        int v = (t >= d) ? part[t - d] : 0;
        __syncthreads();
        part[t] += v;
        __syncthreads();
    }
    int run = (t == 0) ? 0 : part[t - 1];
    for (int i = 0; i < CH; ++i) {
        int idx = base + i;
        if (idx < N_NODES) {
            off[idx] = run;
            run += deg[idx];
        }
    }
    if (t == 1023) off[N_NODES] = part[1023];
}

__global__ __launch_bounds__(256) void fill_kernel(
    const int* __restrict__ src, const int* __restrict__ dst,
    const int* __restrict__ off, int* __restrict__ cursor,
    int* __restrict__ csr_src)
{
    int e = blockIdx.x * 256 + threadIdx.x;
    if (e >= N_EDGES) return;
    int d = dst[e];
    int slot = atomicAdd(&cursor[d], 1);
    csr_src[off[d] + slot] = src[e];
}

// ================= fp32 -> bf16 conversion =================
__global__ __launch_bounds__(256) void cvt_kernel(
    const float* __restrict__ src, unsigned short* __restrict__ dst, int n4)
{
    int i = blockIdx.x * 256 + threadIdx.x;
    if (i >= n4) return;
    float4 v = reinterpret_cast<const float4*>(src)[i];
    ushort4 o;
    o.x = f2bf(v.x); o.y = f2bf(v.y); o.z = f2bf(v.z); o.w = f2bf(v.w);
    reinterpret_cast<ushort4*>(dst)[i] = o;
}

// ================= gather aggregation (bf16 in, fp32 accum, bf16 out) =================
// 16 lanes per node, bf16x8 per lane
__global__ __launch_bounds__(256) void gather_bf16(
    const unsigned short* __restrict__ X, const int* __restrict__ off,
    const int* __restrict__ csr_src, unsigned short* __restrict__ agg)
{
    int gid  = blockIdx.x * 256 + threadIdx.x;
    int node = gid >> 4;
    int l8   = (gid & 15) << 3;
    if (node >= N_NODES) return;
    int s0 = off[node], s1 = off[node + 1];
    float acc[8] = {0.f, 0.f, 0.f, 0.f, 0.f, 0.f, 0.f, 0.f};
    for (int j = s0; j < s1; ++j) {
        int s = csr_src[j];
        bf16x8 v = *reinterpret_cast<const bf16x8*>(X + (size_t)s * F + l8);
#pragma unroll
        for (int r = 0; r < 8; ++r) acc[r] += bf2f((unsigned short)v[r]);
    }
    bf16x8 o;
#pragma unroll
    for (int r = 0; r < 8; ++r) o[r] = (short)f2bf(acc[r]);
    *reinterpret_cast<bf16x8*>(agg + (size_t)node * F + l8) = o;
}

// ================= fused GraphConv via MFMA =================
// H = [relu](AGG@Wrel^T + b + X@Wroot^T), all feature data bf16, acc fp32.
// BM=64 per block, 4 waves in 2x2, wave tile 32x64. Direct-from-global fragments.
template <int RELU>
__global__ __launch_bounds__(256) void conv_mfma(
    const unsigned short* __restrict__ AGGb, const unsigned short* __restrict__ Xb,
    const unsigned short* __restrict__ Wrel, const unsigned short* __restrict__ Wroot,
    const float* __restrict__ brel, unsigned short* __restrict__ H)
{
    const int t    = threadIdx.x;
    const int wave = t >> 6;
    const int lane = t & 63;
    const int wm = wave >> 1, wn = wave & 1;
    const int m0 = blockIdx.x * 64 + wm * 32;
    const int n0 = wn * 64;
    const int lrow = lane & 15;
    const int lk8  = (lane >> 4) << 3;   // k offset within 32-slice: 0,8,16,24

    f32x4 acc[2][4];
#pragma unroll
    for (int mi = 0; mi < 2; ++mi)
#pragma unroll
        for (int ni = 0; ni < 4; ++ni)
            acc[mi][ni] = (f32x4){0.f, 0.f, 0.f, 0.f};

#pragma unroll
    for (int p = 0; p < 2; ++p) {
        const unsigned short* A = p ? Xb : AGGb;
        const unsigned short* W = p ? Wroot : Wrel;
#pragma unroll
        for (int ks = 0; ks < 4; ++ks) {
            int k0 = ks * 32 + lk8;
            bf16x8 a[2], b[4];
#pragma unroll
            for (int mi = 0; mi < 2; ++mi)
                a[mi] = *reinterpret_cast<const bf16x8*>(
                    A + (size_t)(m0 + mi * 16 + lrow) * F + k0);
#pragma unroll
            for (int ni = 0; ni < 4; ++ni)
                b[ni] = *reinterpret_cast<const bf16x8*>(
                    W + (size_t)(n0 + ni * 16 + lrow) * F + k0);
#pragma unroll
            for (int mi = 0; mi < 2; ++mi)
#pragma unroll
                for (int ni = 0; ni < 4; ++ni)
                    acc[mi][ni] = __builtin_amdgcn_mfma_f32_16x16x32_bf16(
                        a[mi], b[ni], acc[mi][ni], 0, 0, 0);
        }
    }

    const int r0 = (lane >> 4) << 2;   // C/D: row = (lane>>4)*4 + reg
#pragma unroll
    for (int ni = 0; ni < 4; ++ni) {
        int col = n0 + ni * 16 + lrow;
        float bb = brel[col];
#pragma unroll
        for (int mi = 0; mi < 2; ++mi) {
#pragma unroll
            for (int r = 0; r < 4; ++r) {
                int row = m0 + mi * 16 + r0 + r;
                if (row < N_NODES) {
                    float v = acc[mi][ni][r] + bb;
                    if (RELU) v = fmaxf(v, 0.f);
                    H[(size_t)row * F + col] = f2bf(v);
                }
            }
        }
    }
}

// ================= mean pool (bf16 in, fp32 out) =================
__global__ __launch_bounds__(256) void pool_kernel(
    const unsigned short* __restrict__ H, const int* __restrict__ batch,
    float* __restrict__ G)
{
    int g = blockIdx.x;
    int lo = 0, hi = N_NODES;
    while (lo < hi) { int m = (lo + hi) >> 1; if (batch[m] < g) lo = m + 1; else hi = m; }
    int start = lo;
    hi = N_NODES;
    while (lo < hi) { int m = (lo + hi) >> 1; if (batch[m] < g + 1) lo = m + 1; else hi = m; }
    int end = lo;

    int l8 = (threadIdx.x & 15) << 3;
    int rg = threadIdx.x >> 4;        // 0..15
    float acc[8] = {0.f, 0.f, 0.f, 0.f, 0.f, 0.f, 0.f, 0.f};
    for (int i = start + rg; i < end; i += 16) {
        bf16x8 v = *reinterpret_cast<const bf16x8*>(H + (size_t)i * F + l8);
#pragma unroll
        for (int r = 0; r < 8; ++r) acc[r] += bf2f((unsigned short)v[r]);
    }
    __shared__ float sh[16][F];
#pragma unroll
    for (int r = 0; r < 8; ++r) sh[rg][l8 + r] = acc[r];
    __syncthreads();
    if (threadIdx.x < F) {
        int f = threadIdx.x;
        float s = 0.f;
#pragma unroll
        for (int k = 0; k < 16; ++k) s += sh[k][f];
        float cnt = (float)(end - start);
        G[g * F + f] = s / fmaxf(cnt, 1.f);
    }
}

// ================= head =================
__global__ __launch_bounds__(640) void head_kernel(
    const float* __restrict__ G, const float* __restrict__ Wl,
    const float* __restrict__ bl, float* __restrict__ out)
{
    int t = threadIdx.x;
    int g = t / N_CLASSES;
    int c = t % N_CLASSES;
    float s = bl[c];
#pragma unroll 8
    for (int k = 0; k < F; ++k) s += G[g * F + k] * Wl[c * F + k];
    out[t] = s;
}

extern "C" void kernel_launch(void* const* d_in, const int* in_sizes, int n_in,
                              void* d_out, int out_size, void* d_ws, size_t ws_size,
                              hipStream_t stream)
{
    const float* x     = (const float*)d_in[0];
    const int*   edge  = (const int*)d_in[1];
    const int*   src   = edge;
    const int*   dst   = edge + N_EDGES;
    const int*   batch = (const int*)d_in[2];
    const float* W1r = (const float*)d_in[3];
    const float* b1  = (const float*)d_in[4];
    const float* W1o = (const float*)d_in[5];
    const float* W2r = (const float*)d_in[6];
    const float* b2  = (const float*)d_in[7];
    const float* W2o = (const float*)d_in[8];
    const float* W3r = (const float*)d_in[9];
    const float* b3  = (const float*)d_in[10];
    const float* W3o = (const float*)d_in[11];
    const float* Wl  = (const float*)d_in[12];
    const float* bl  = (const float*)d_in[13];
    float* out = (float*)d_out;

    char* ws = (char*)d_ws;
    const size_t fb = (size_t)NPAD * F * sizeof(unsigned short);   // 12.8 MB
    unsigned short* Xb   = (unsigned short*)ws;
    unsigned short* AGGb = (unsigned short*)(ws + fb);
    unsigned short* H1b  = (unsigned short*)(ws + 2 * fb);
    unsigned short* H2b  = (unsigned short*)(ws + 3 * fb);
    char* p = ws + 4 * fb;
    unsigned short* Wb[6];
    for (int i = 0; i < 6; ++i) { Wb[i] = (unsigned short*)p; p += (size_t)F * F * sizeof(unsigned short); }
    float* G = (float*)p;                p += (size_t)N_GRAPHS * F * sizeof(float);
    int* deg     = (int*)p;              p += (size_t)N_NODES * sizeof(int);
    int* cursor  = (int*)p;              p += (size_t)N_NODES * sizeof(int);
    int* off     = (int*)p;              p += (size_t)(N_NODES + 1) * sizeof(int);
    int* csr_src = (int*)p;

    const int edgeBlocks   = (N_EDGES + 255) / 256;    // 2344
    const int gatherBlocks = (N_NODES * 16) / 256;     // 3125
    const int convBlocks   = NPAD / 64;                // 782
    const int xCvtBlocks   = (N_NODES * F / 4) / 256;  // 6250
    const int wCvtBlocks   = (F * F / 4 + 255) / 256;  // 16

    // ---- conversions ----
    cvt_kernel<<<xCvtBlocks, 256, 0, stream>>>(x, Xb, N_NODES * F / 4);
    cvt_kernel<<<wCvtBlocks, 256, 0, stream>>>(W1r, Wb[0], F * F / 4);
    cvt_kernel<<<wCvtBlocks, 256, 0, stream>>>(W1o, Wb[1], F * F / 4);
    cvt_kernel<<<wCvtBlocks, 256, 0, stream>>>(W2r, Wb[2], F * F / 4);
    cvt_kernel<<<wCvtBlocks, 256, 0, stream>>>(W2o, Wb[3], F * F / 4);
    cvt_kernel<<<wCvtBlocks, 256, 0, stream>>>(W3r, Wb[4], F * F / 4);
    cvt_kernel<<<wCvtBlocks, 256, 0, stream>>>(W3o, Wb[5], F * F / 4);

    // ---- CSR build ----
    hipMemsetAsync(deg, 0, (size_t)N_NODES * sizeof(int), stream);
    hipMemsetAsync(cursor, 0, (size_t)N_NODES * sizeof(int), stream);
    hist_kernel<<<edgeBlocks, 256, 0, stream>>>(dst, deg);
    scan_kernel<<<1, 1024, 0, stream>>>(deg, off);
    fill_kernel<<<edgeBlocks, 256, 0, stream>>>(src, dst, off, cursor, csr_src);

    // ---- layer 1 ----
    gather_bf16<<<gatherBlocks, 256, 0, stream>>>(Xb, off, csr_src, AGGb);
    conv_mfma<1><<<convBlocks, 256, 0, stream>>>(AGGb, Xb, Wb[0], Wb[1], b1, H1b);
    // ---- layer 2 ----
    gather_bf16<<<gatherBlocks, 256, 0, stream>>>(H1b, off, csr_src, AGGb);
    conv_mfma<1><<<convBlocks, 256, 0, stream>>>(AGGb, H1b, Wb[2], Wb[3], b2, H2b);
    // ---- layer 3 ----
    gather_bf16<<<gatherBlocks, 256, 0, stream>>>(H2b, off, csr_src, AGGb);
    conv_mfma<0><<<convBlocks, 256, 0, stream>>>(AGGb, H2b, Wb[4], Wb[5], b3, H1b);
    // ---- pool + head ----
    pool_kernel<<<N_GRAPHS, 256, 0, stream>>>(H1b, batch, G);
    head_kernel<<<1, 640, 0, stream>>>(G, Wl, bl, out);
}

// Round 4
// 295.016 us; speedup vs baseline: 11.9566x; 1.3213x over previous
//
#include <hip/hip_runtime.h>
#include <hip/hip_bf16.h>

#define N_NODES   50000
#define N_EDGES   600000
#define F         128
#define N_GRAPHS  64
#define N_CLASSES 10
#define NPAD      50048           // 782 * 64
#define NB_SCAN   196             // ceil(50000/256)

typedef __attribute__((ext_vector_type(8))) short bf16x8;
typedef __attribute__((ext_vector_type(4))) float f32x4;

static __device__ __forceinline__ unsigned short f2bf(float f) {
    __hip_bfloat16 h = __float2bfloat16(f);
    return *reinterpret_cast<unsigned short*>(&h);
}
static __device__ __forceinline__ float bf2f(unsigned short u) {
    return __uint_as_float(((unsigned)u) << 16);
}

// ================= CSR build =================
__global__ __launch_bounds__(256) void hist_kernel(
    const int* __restrict__ dst, int* __restrict__ deg)
{
    int e = blockIdx.x * 256 + threadIdx.x;
    if (e >= N_EDGES) return;
    atomicAdd(&deg[dst[e]], 1);
}

// ---- hierarchical scan: A (block-local), B (block sums), C (add base) ----
__global__ __launch_bounds__(256) void scanA_kernel(
    const int* __restrict__ deg, int* __restrict__ locEx, int* __restrict__ blockSum)
{
    __shared__ int sh[256];
    int t = threadIdx.x;
    int idx = blockIdx.x * 256 + t;
    int v = (idx < N_NODES) ? deg[idx] : 0;
    sh[t] = v;
    __syncthreads();
#pragma unroll
    for (int d = 1; d < 256; d <<= 1) {
        int u = (t >= d) ? sh[t - d] : 0;
        __syncthreads();
        sh[t] += u;
        __syncthreads();
    }
    if (idx < N_NODES) locEx[idx] = sh[t] - v;
    if (t == 255) blockSum[blockIdx.x] = sh[255];
}

__global__ __launch_bounds__(256) void scanB_kernel(
    int* __restrict__ blockSum, int* __restrict__ offLast)
{
    __shared__ int sh[256];
    int t = threadIdx.x;
    int v = (t < NB_SCAN) ? blockSum[t] : 0;
    sh[t] = v;
    __syncthreads();
#pragma unroll
    for (int d = 1; d < 256; d <<= 1) {
        int u = (t >= d) ? sh[t - d] : 0;
        __syncthreads();
        sh[t] += u;
        __syncthreads();
    }
    if (t < NB_SCAN) blockSum[t] = sh[t] - v;   // exclusive base per block
    if (t == 255) *offLast = sh[255];           // total == N_EDGES -> off[N_NODES]
}

__global__ __launch_bounds__(256) void scanC_kernel(
    const int* __restrict__ locEx, const int* __restrict__ blockSum,
    int* __restrict__ off)
{
    int idx = blockIdx.x * 256 + threadIdx.x;
    if (idx < N_NODES) off[idx] = locEx[idx] + blockSum[blockIdx.x];
}

__global__ __launch_bounds__(256) void fill_kernel(
    const int* __restrict__ src, const int* __restrict__ dst,
    const int* __restrict__ off, int* __restrict__ cursor,
    int* __restrict__ csr_src)
{
    int e = blockIdx.x * 256 + threadIdx.x;
    if (e >= N_EDGES) return;
    int d = dst[e];
    int slot = atomicAdd(&cursor[d], 1);
    csr_src[off[d] + slot] = src[e];
}

// ================= fp32 -> bf16 conversion =================
__global__ __launch_bounds__(256) void cvt_kernel(
    const float* __restrict__ src, unsigned short* __restrict__ dst, int n4)
{
    int i = blockIdx.x * 256 + threadIdx.x;
    if (i >= n4) return;
    float4 v = reinterpret_cast<const float4*>(src)[i];
    ushort4 o;
    o.x = f2bf(v.x); o.y = f2bf(v.y); o.z = f2bf(v.z); o.w = f2bf(v.w);
    reinterpret_cast<ushort4*>(dst)[i] = o;
}

// all six FxF weight matrices in one dispatch; dst is 6 contiguous FxF panels
__global__ __launch_bounds__(256) void cvt_w_kernel(
    const float* __restrict__ W0, const float* __restrict__ W1,
    const float* __restrict__ W2, const float* __restrict__ W3,
    const float* __restrict__ W4, const float* __restrict__ W5,
    unsigned short* __restrict__ dst)
{
    const int PER = (F * F / 4) / 256;        // 16 blocks per matrix
    int mat = blockIdx.x / PER;
    int i   = (blockIdx.x % PER) * 256 + threadIdx.x;   // float4 index within matrix
    const float* W = (mat == 0) ? W0 : (mat == 1) ? W1 : (mat == 2) ? W2
                   : (mat == 3) ? W3 : (mat == 4) ? W4 : W5;
    float4 v = reinterpret_cast<const float4*>(W)[i];
    ushort4 o;
    o.x = f2bf(v.x); o.y = f2bf(v.y); o.z = f2bf(v.z); o.w = f2bf(v.w);
    reinterpret_cast<ushort4*>(dst + (size_t)mat * F * F)[i] = o;
}

// ================= gather aggregation (bf16 in, fp32 accum, bf16 out) =================
__global__ __launch_bounds__(256) void gather_bf16(
    const unsigned short* __restrict__ X, const int* __restrict__ off,
    const int* __restrict__ csr_src, unsigned short* __restrict__ agg)
{
    int gid  = blockIdx.x * 256 + threadIdx.x;
    int node = gid >> 4;
    int l8   = (gid & 15) << 3;
    if (node >= N_NODES) return;
    int s0 = off[node], s1 = off[node + 1];
    float acc[8] = {0.f, 0.f, 0.f, 0.f, 0.f, 0.f, 0.f, 0.f};
    for (int j = s0; j < s1; ++j) {
        int s = csr_src[j];
        bf16x8 v = *reinterpret_cast<const bf16x8*>(X + (size_t)s * F + l8);
#pragma unroll
        for (int r = 0; r < 8; ++r) acc[r] += bf2f((unsigned short)v[r]);
    }
    bf16x8 o;
#pragma unroll
    for (int r = 0; r < 8; ++r) o[r] = (short)f2bf(acc[r]);
    *reinterpret_cast<bf16x8*>(agg + (size_t)node * F + l8) = o;
}

// ================= fused GraphConv via MFMA =================
template <int RELU>
__global__ __launch_bounds__(256) void conv_mfma(
    const unsigned short* __restrict__ AGGb, const unsigned short* __restrict__ Xb,
    const unsigned short* __restrict__ Wrel, const unsigned short* __restrict__ Wroot,
    const float* __restrict__ brel, unsigned short* __restrict__ H)
{
    const int t    = threadIdx.x;
    const int wave = t >> 6;
    const int lane = t & 63;
    const int wm = wave >> 1, wn = wave & 1;
    const int m0 = blockIdx.x * 64 + wm * 32;
    const int n0 = wn * 64;
    const int lrow = lane & 15;
    const int lk8  = (lane >> 4) << 3;

    f32x4 acc[2][4];
#pragma unroll
    for (int mi = 0; mi < 2; ++mi)
#pragma unroll
        for (int ni = 0; ni < 4; ++ni)
            acc[mi][ni] = (f32x4){0.f, 0.f, 0.f, 0.f};

#pragma unroll
    for (int p = 0; p < 2; ++p) {
        const unsigned short* A = p ? Xb : AGGb;
        const unsigned short* W = p ? Wroot : Wrel;
#pragma unroll
        for (int ks = 0; ks < 4; ++ks) {
            int k0 = ks * 32 + lk8;
            bf16x8 a[2], b[4];
#pragma unroll
            for (int mi = 0; mi < 2; ++mi)
                a[mi] = *reinterpret_cast<const bf16x8*>(
                    A + (size_t)(m0 + mi * 16 + lrow) * F + k0);
#pragma unroll
            for (int ni = 0; ni < 4; ++ni)
                b[ni] = *reinterpret_cast<const bf16x8*>(
                    W + (size_t)(n0 + ni * 16 + lrow) * F + k0);
#pragma unroll
            for (int mi = 0; mi < 2; ++mi)
#pragma unroll
                for (int ni = 0; ni < 4; ++ni)
                    acc[mi][ni] = __builtin_amdgcn_mfma_f32_16x16x32_bf16(
                        a[mi], b[ni], acc[mi][ni], 0, 0, 0);
        }
    }

    const int r0 = (lane >> 4) << 2;
#pragma unroll
    for (int ni = 0; ni < 4; ++ni) {
        int col = n0 + ni * 16 + lrow;
        float bb = brel[col];
#pragma unroll
        for (int mi = 0; mi < 2; ++mi) {
#pragma unroll
            for (int r = 0; r < 4; ++r) {
                int row = m0 + mi * 16 + r0 + r;
                if (row < N_NODES) {
                    float v = acc[mi][ni][r] + bb;
                    if (RELU) v = fmaxf(v, 0.f);
                    H[(size_t)row * F + col] = f2bf(v);
                }
            }
        }
    }
}

// ================= mean pool (bf16 in, fp32 out) =================
__global__ __launch_bounds__(256) void pool_kernel(
    const unsigned short* __restrict__ H, const int* __restrict__ batch,
    float* __restrict__ G)
{
    int g = blockIdx.x;
    int lo = 0, hi = N_NODES;
    while (lo < hi) { int m = (lo + hi) >> 1; if (batch[m] < g) lo = m + 1; else hi = m; }
    int start = lo;
    hi = N_NODES;
    while (lo < hi) { int m = (lo + hi) >> 1; if (batch[m] < g + 1) lo = m + 1; else hi = m; }
    int end = lo;

    int l8 = (threadIdx.x & 15) << 3;
    int rg = threadIdx.x >> 4;
    float acc[8] = {0.f, 0.f, 0.f, 0.f, 0.f, 0.f, 0.f, 0.f};
    for (int i = start + rg; i < end; i += 16) {
        bf16x8 v = *reinterpret_cast<const bf16x8*>(H + (size_t)i * F + l8);
#pragma unroll
        for (int r = 0; r < 8; ++r) acc[r] += bf2f((unsigned short)v[r]);
    }
    __shared__ float sh[16][F];
#pragma unroll
    for (int r = 0; r < 8; ++r) sh[rg][l8 + r] = acc[r];
    __syncthreads();
    if (threadIdx.x < F) {
        int f = threadIdx.x;
        float s = 0.f;
#pragma unroll
        for (int k = 0; k < 16; ++k) s += sh[k][f];
        float cnt = (float)(end - start);
        G[g * F + f] = s / fmaxf(cnt, 1.f);
    }
}

// ================= head =================
__global__ __launch_bounds__(640) void head_kernel(
    const float* __restrict__ G, const float* __restrict__ Wl,
    const float* __restrict__ bl, float* __restrict__ out)
{
    int t = threadIdx.x;
    int g = t / N_CLASSES;
    int c = t % N_CLASSES;
    float s = bl[c];
#pragma unroll 8
    for (int k = 0; k < F; ++k) s += G[g * F + k] * Wl[c * F + k];
    out[t] = s;
}

extern "C" void kernel_launch(void* const* d_in, const int* in_sizes, int n_in,
                              void* d_out, int out_size, void* d_ws, size_t ws_size,
                              hipStream_t stream)
{
    const float* x     = (const float*)d_in[0];
    const int*   edge  = (const int*)d_in[1];
    const int*   src   = edge;
    const int*   dst   = edge + N_EDGES;
    const int*   batch = (const int*)d_in[2];
    const float* W1r = (const float*)d_in[3];
    const float* b1  = (const float*)d_in[4];
    const float* W1o = (const float*)d_in[5];
    const float* W2r = (const float*)d_in[6];
    const float* b2  = (const float*)d_in[7];
    const float* W2o = (const float*)d_in[8];
    const float* W3r = (const float*)d_in[9];
    const float* b3  = (const float*)d_in[10];
    const float* W3o = (const float*)d_in[11];
    const float* Wl  = (const float*)d_in[12];
    const float* bl  = (const float*)d_in[13];
    float* out = (float*)d_out;

    char* ws = (char*)d_ws;
    const size_t fb = (size_t)NPAD * F * sizeof(unsigned short);   // 12.8 MB
    unsigned short* Xb   = (unsigned short*)ws;
    unsigned short* AGGb = (unsigned short*)(ws + fb);
    unsigned short* H1b  = (unsigned short*)(ws + 2 * fb);
    unsigned short* H2b  = (unsigned short*)(ws + 3 * fb);
    char* p = ws + 4 * fb;
    unsigned short* Wb = (unsigned short*)p;   // 6 contiguous FxF panels
    p += (size_t)6 * F * F * sizeof(unsigned short);
    float* G = (float*)p;                p += (size_t)N_GRAPHS * F * sizeof(float);
    int* deg     = (int*)p;              p += (size_t)N_NODES * sizeof(int);
    int* cursor  = (int*)p;              p += (size_t)N_NODES * sizeof(int);  // contiguous w/ deg
    int* off     = (int*)p;              p += (size_t)(N_NODES + 1) * sizeof(int);
    int* locEx   = (int*)p;              p += (size_t)N_NODES * sizeof(int);
    int* blockSum= (int*)p;              p += (size_t)256 * sizeof(int);
    int* csr_src = (int*)p;

    const int edgeBlocks   = (N_EDGES + 255) / 256;    // 2344
    const int gatherBlocks = (N_NODES * 16) / 256;     // 3125
    const int convBlocks   = NPAD / 64;                // 782
    const int xCvtBlocks   = (N_NODES * F / 4) / 256;  // 6250
    const int wCvtBlocks   = 6 * (F * F / 4) / 256;    // 96

    // ---- conversions ----
    cvt_kernel<<<xCvtBlocks, 256, 0, stream>>>(x, Xb, N_NODES * F / 4);
    cvt_w_kernel<<<wCvtBlocks, 256, 0, stream>>>(W1r, W1o, W2r, W2o, W3r, W3o, Wb);

    // ---- CSR build ----
    hipMemsetAsync(deg, 0, (size_t)2 * N_NODES * sizeof(int), stream);  // deg + cursor
    hist_kernel<<<edgeBlocks, 256, 0, stream>>>(dst, deg);
    scanA_kernel<<<NB_SCAN, 256, 0, stream>>>(deg, locEx, blockSum);
    scanB_kernel<<<1, 256, 0, stream>>>(blockSum, off + N_NODES);
    scanC_kernel<<<NB_SCAN, 256, 0, stream>>>(locEx, blockSum, off);
    fill_kernel<<<edgeBlocks, 256, 0, stream>>>(src, dst, off, cursor, csr_src);

    // ---- layer 1 ----
    gather_bf16<<<gatherBlocks, 256, 0, stream>>>(Xb, off, csr_src, AGGb);
    conv_mfma<1><<<convBlocks, 256, 0, stream>>>(AGGb, Xb, Wb + 0 * F * F, Wb + 1 * F * F, b1, H1b);
    // ---- layer 2 ----
    gather_bf16<<<gatherBlocks, 256, 0, stream>>>(H1b, off, csr_src, AGGb);
    conv_mfma<1><<<convBlocks, 256, 0, stream>>>(AGGb, H1b, Wb + 2 * F * F, Wb + 3 * F * F, b2, H2b);
    // ---- layer 3 ----
    gather_bf16<<<gatherBlocks, 256, 0, stream>>>(H2b, off, csr_src, AGGb);
    conv_mfma<0><<<convBlocks, 256, 0, stream>>>(AGGb, H2b, Wb + 4 * F * F, Wb + 5 * F * F, b3, H1b);
    // ---- pool + head ----
    pool_kernel<<<N_GRAPHS, 256, 0, stream>>>(H1b, batch, G);
    head_kernel<<<1, 640, 0, stream>>>(G, Wl, bl, out);
}

// Round 5
// 253.185 us; speedup vs baseline: 13.9320x; 1.1652x over previous
//
#include <hip/hip_runtime.h>
#include <hip/hip_bf16.h>

#define N_NODES   50000
#define N_EDGES   600000
#define F         128
#define N_GRAPHS  64
#define N_CLASSES 10
#define NPAD      50048           // 782 * 64
#define NB_SCAN   196             // ceil(50000/256)
#define XCVT_BLOCKS 6250          // N_NODES*F/4/256

typedef __attribute__((ext_vector_type(8))) short bf16x8;
typedef __attribute__((ext_vector_type(4))) float f32x4;

static __device__ __forceinline__ unsigned short f2bf(float f) {
    __hip_bfloat16 h = __float2bfloat16(f);
    return *reinterpret_cast<unsigned short*>(&h);
}
static __device__ __forceinline__ float bf2f(unsigned short u) {
    return __uint_as_float(((unsigned)u) << 16);
}

// ================= CSR build =================
__global__ __launch_bounds__(256) void hist_kernel(
    const int* __restrict__ dst, int* __restrict__ deg)
{
    int e = blockIdx.x * 256 + threadIdx.x;
    if (e >= N_EDGES) return;
    atomicAdd(&deg[dst[e]], 1);
}

__global__ __launch_bounds__(256) void scanA_kernel(
    const int* __restrict__ deg, int* __restrict__ locEx, int* __restrict__ blockSum)
{
    __shared__ int sh[256];
    int t = threadIdx.x;
    int idx = blockIdx.x * 256 + t;
    int v = (idx < N_NODES) ? deg[idx] : 0;
    sh[t] = v;
    __syncthreads();
#pragma unroll
    for (int d = 1; d < 256; d <<= 1) {
        int u = (t >= d) ? sh[t - d] : 0;
        __syncthreads();
        sh[t] += u;
        __syncthreads();
    }
    if (idx < N_NODES) locEx[idx] = sh[t] - v;
    if (t == 255) blockSum[blockIdx.x] = sh[255];
}

// fused: every block scans the 196 block sums in LDS, then adds its base
__global__ __launch_bounds__(256) void scanBC_kernel(
    const int* __restrict__ locEx, const int* __restrict__ blockSum,
    int* __restrict__ off)
{
    __shared__ int sh[256];
    int t = threadIdx.x;
    int v = (t < NB_SCAN) ? blockSum[t] : 0;
    sh[t] = v;
    __syncthreads();
#pragma unroll
    for (int d = 1; d < 256; d <<= 1) {
        int u = (t >= d) ? sh[t - d] : 0;
        __syncthreads();
        sh[t] += u;
        __syncthreads();
    }
    // sh = inclusive scan of block sums
    int myVal  = blockSum[blockIdx.x];
    int base   = sh[blockIdx.x] - myVal;       // exclusive base for this block
    int idx = blockIdx.x * 256 + t;
    if (idx < N_NODES) off[idx] = locEx[idx] + base;
    if (blockIdx.x == 0 && t == 0) off[N_NODES] = sh[NB_SCAN - 1];
}

__global__ __launch_bounds__(256) void fill_kernel(
    const int* __restrict__ src, const int* __restrict__ dst,
    const int* __restrict__ off, int* __restrict__ cursor,
    int* __restrict__ csr_src)
{
    int e = blockIdx.x * 256 + threadIdx.x;
    if (e >= N_EDGES) return;
    int d = dst[e];
    int slot = atomicAdd(&cursor[d], 1);
    csr_src[off[d] + slot] = src[e];
}

// ================= all fp32->bf16 conversions in ONE dispatch =================
__global__ __launch_bounds__(256) void cvt_all_kernel(
    const float* __restrict__ x,
    const float* __restrict__ W0, const float* __restrict__ W1,
    const float* __restrict__ W2, const float* __restrict__ W3,
    const float* __restrict__ W4, const float* __restrict__ W5,
    unsigned short* __restrict__ Xb, unsigned short* __restrict__ Wb)
{
    int b = blockIdx.x;
    if (b < XCVT_BLOCKS) {
        int i = b * 256 + threadIdx.x;
        float4 v = reinterpret_cast<const float4*>(x)[i];
        ushort4 o;
        o.x = f2bf(v.x); o.y = f2bf(v.y); o.z = f2bf(v.z); o.w = f2bf(v.w);
        reinterpret_cast<ushort4*>(Xb)[i] = o;
    } else {
        const int PER = (F * F / 4) / 256;   // 16
        int bb  = b - XCVT_BLOCKS;
        int mat = bb / PER;
        int i   = (bb % PER) * 256 + threadIdx.x;
        const float* W = (mat == 0) ? W0 : (mat == 1) ? W1 : (mat == 2) ? W2
                       : (mat == 3) ? W3 : (mat == 4) ? W4 : W5;
        float4 v = reinterpret_cast<const float4*>(W)[i];
        ushort4 o;
        o.x = f2bf(v.x); o.y = f2bf(v.y); o.z = f2bf(v.z); o.w = f2bf(v.w);
        reinterpret_cast<ushort4*>(Wb + (size_t)mat * F * F)[i] = o;
    }
}

// ================= fused gather + GraphConv via MFMA =================
// Phase 1: gather AGG rows for this block's 64 output rows into LDS (bf16,
//          XOR-swizzled). Phase 2: H = [relu](AGG@Wrel^T + b + X@Wroot^T).
template <int RELU>
__global__ __launch_bounds__(256) void conv_fused(
    const unsigned short* __restrict__ Xb,    // source features (gather + root)
    const int* __restrict__ off, const int* __restrict__ csr_src,
    const unsigned short* __restrict__ Wrel, const unsigned short* __restrict__ Wroot,
    const float* __restrict__ brel, unsigned short* __restrict__ H)
{
    __shared__ char AsRaw[64 * 256];   // As[64][128] bf16, byte-XOR swizzled rows
    const int t = threadIdx.x;
    const int mBase = blockIdx.x * 64;

    // ---- phase 1: per-row neighbor sum (4 threads/row, 32 feats each) ----
    {
        const int r = t >> 2;
        const int q = t & 3;
        int row = mBase + r;
        float acc[32];
#pragma unroll
        for (int i = 0; i < 32; ++i) acc[i] = 0.f;
        if (row < N_NODES) {
            int s0 = off[row], s1 = off[row + 1];
            for (int j = s0; j < s1; ++j) {
                int s = csr_src[j];
                const bf16x8* base = reinterpret_cast<const bf16x8*>(
                    Xb + (size_t)s * F + q * 32);
#pragma unroll
                for (int c = 0; c < 4; ++c) {
                    bf16x8 v = base[c];
#pragma unroll
                    for (int e = 0; e < 8; ++e) acc[c * 8 + e] += bf2f((unsigned short)v[e]);
                }
            }
        }
#pragma unroll
        for (int c = 0; c < 4; ++c) {
            bf16x8 o;
#pragma unroll
            for (int e = 0; e < 8; ++e) o[e] = (short)f2bf(acc[c * 8 + e]);
            int bytecol = (q * 64 + c * 16) ^ ((r & 7) << 4);
            *reinterpret_cast<bf16x8*>(AsRaw + r * 256 + bytecol) = o;
        }
    }
    __syncthreads();

    // ---- phase 2: MFMA, 4 waves in 2x2, wave tile 32x64 ----
    const int wave = t >> 6;
    const int lane = t & 63;
    const int wm = wave >> 1, wn = wave & 1;
    const int m0l = wm * 32;           // local row base within the 64-row tile
    const int n0  = wn * 64;
    const int lrow = lane & 15;
    const int lk8  = (lane >> 4) << 3;

    f32x4 acc[2][4];
#pragma unroll
    for (int mi = 0; mi < 2; ++mi)
#pragma unroll
        for (int ni = 0; ni < 4; ++ni)
            acc[mi][ni] = (f32x4){0.f, 0.f, 0.f, 0.f};

#pragma unroll
    for (int p = 0; p < 2; ++p) {
        const unsigned short* W = p ? Wroot : Wrel;
#pragma unroll
        for (int ks = 0; ks < 4; ++ks) {
            int k0 = ks * 32 + lk8;
            bf16x8 a[2], b[4];
#pragma unroll
            for (int mi = 0; mi < 2; ++mi) {
                int rl = m0l + mi * 16 + lrow;
                if (p == 0) {
                    int bytecol = (k0 * 2) ^ ((rl & 7) << 4);
                    a[mi] = *reinterpret_cast<const bf16x8*>(AsRaw + rl * 256 + bytecol);
                } else {
                    a[mi] = *reinterpret_cast<const bf16x8*>(
                        Xb + (size_t)(mBase + rl) * F + k0);
                }
            }
#pragma unroll
            for (int ni = 0; ni < 4; ++ni)
                b[ni] = *reinterpret_cast<const bf16x8*>(
                    W + (size_t)(n0 + ni * 16 + lrow) * F + k0);
#pragma unroll
            for (int mi = 0; mi < 2; ++mi)
#pragma unroll
                for (int ni = 0; ni < 4; ++ni)
                    acc[mi][ni] = __builtin_amdgcn_mfma_f32_16x16x32_bf16(
                        a[mi], b[ni], acc[mi][ni], 0, 0, 0);
        }
    }

    const int r0 = (lane >> 4) << 2;   // C/D: row = (lane>>4)*4 + reg
#pragma unroll
    for (int ni = 0; ni < 4; ++ni) {
        int col = n0 + ni * 16 + lrow;
        float bb = brel[col];
#pragma unroll
        for (int mi = 0; mi < 2; ++mi) {
#pragma unroll
            for (int r = 0; r < 4; ++r) {
                int row = mBase + m0l + mi * 16 + r0 + r;
                if (row < N_NODES) {
                    float v = acc[mi][ni][r] + bb;
                    if (RELU) v = fmaxf(v, 0.f);
                    H[(size_t)row * F + col] = f2bf(v);
                }
            }
        }
    }
}

// ================= mean pool (bf16 in, fp32 out) =================
__global__ __launch_bounds__(256) void pool_kernel(
    const unsigned short* __restrict__ H, const int* __restrict__ batch,
    float* __restrict__ G)
{
    int g = blockIdx.x;
    int lo = 0, hi = N_NODES;
    while (lo < hi) { int m = (lo + hi) >> 1; if (batch[m] < g) lo = m + 1; else hi = m; }
    int start = lo;
    hi = N_NODES;
    while (lo < hi) { int m = (lo + hi) >> 1; if (batch[m] < g + 1) lo = m + 1; else hi = m; }
    int end = lo;

    int l8 = (threadIdx.x & 15) << 3;
    int rg = threadIdx.x >> 4;
    float acc[8] = {0.f, 0.f, 0.f, 0.f, 0.f, 0.f, 0.f, 0.f};
    for (int i = start + rg; i < end; i += 16) {
        bf16x8 v = *reinterpret_cast<const bf16x8*>(H + (size_t)i * F + l8);
#pragma unroll
        for (int r = 0; r < 8; ++r) acc[r] += bf2f((unsigned short)v[r]);
    }
    __shared__ float sh[16][F];
#pragma unroll
    for (int r = 0; r < 8; ++r) sh[rg][l8 + r] = acc[r];
    __syncthreads();
    if (threadIdx.x < F) {
        int f = threadIdx.x;
        float s = 0.f;
#pragma unroll
        for (int k = 0; k < 16; ++k) s += sh[k][f];
        float cnt = (float)(end - start);
        G[g * F + f] = s / fmaxf(cnt, 1.f);
    }
}

// ================= head =================
__global__ __launch_bounds__(640) void head_kernel(
    const float* __restrict__ G, const float* __restrict__ Wl,
    const float* __restrict__ bl, float* __restrict__ out)
{
    int t = threadIdx.x;
    int g = t / N_CLASSES;
    int c = t % N_CLASSES;
    float s = bl[c];
#pragma unroll 8
    for (int k = 0; k < F; ++k) s += G[g * F + k] * Wl[c * F + k];
    out[t] = s;
}

extern "C" void kernel_launch(void* const* d_in, const int* in_sizes, int n_in,
                              void* d_out, int out_size, void* d_ws, size_t ws_size,
                              hipStream_t stream)
{
    const float* x     = (const float*)d_in[0];
    const int*   edge  = (const int*)d_in[1];
    const int*   src   = edge;
    const int*   dst   = edge + N_EDGES;
    const int*   batch = (const int*)d_in[2];
    const float* W1r = (const float*)d_in[3];
    const float* b1  = (const float*)d_in[4];
    const float* W1o = (const float*)d_in[5];
    const float* W2r = (const float*)d_in[6];
    const float* b2  = (const float*)d_in[7];
    const float* W2o = (const float*)d_in[8];
    const float* W3r = (const float*)d_in[9];
    const float* b3  = (const float*)d_in[10];
    const float* W3o = (const float*)d_in[11];
    const float* Wl  = (const float*)d_in[12];
    const float* bl  = (const float*)d_in[13];
    float* out = (float*)d_out;

    char* ws = (char*)d_ws;
    const size_t fb = (size_t)NPAD * F * sizeof(unsigned short);   // 12.8 MB
    unsigned short* Xb  = (unsigned short*)ws;
    unsigned short* H1b = (unsigned short*)(ws + fb);
    unsigned short* H2b = (unsigned short*)(ws + 2 * fb);
    char* p = ws + 3 * fb;
    unsigned short* Wb = (unsigned short*)p;   // 6 contiguous FxF panels
    p += (size_t)6 * F * F * sizeof(unsigned short);
    float* G = (float*)p;                p += (size_t)N_GRAPHS * F * sizeof(float);
    int* deg     = (int*)p;              p += (size_t)N_NODES * sizeof(int);
    int* cursor  = (int*)p;              p += (size_t)N_NODES * sizeof(int);  // contiguous w/ deg
    int* off     = (int*)p;              p += (size_t)(N_NODES + 1) * sizeof(int);
    int* locEx   = (int*)p;              p += (size_t)N_NODES * sizeof(int);
    int* blockSum= (int*)p;              p += (size_t)256 * sizeof(int);
    int* csr_src = (int*)p;

    const int edgeBlocks = (N_EDGES + 255) / 256;            // 2344
    const int convBlocks = NPAD / 64;                        // 782
    const int cvtBlocks  = XCVT_BLOCKS + 6 * (F * F / 4) / 256;  // 6250 + 96

    // ---- conversions (one dispatch) ----
    cvt_all_kernel<<<cvtBlocks, 256, 0, stream>>>(x, W1r, W1o, W2r, W2o, W3r, W3o, Xb, Wb);

    // ---- CSR build ----
    hipMemsetAsync(deg, 0, (size_t)2 * N_NODES * sizeof(int), stream);  // deg + cursor
    hist_kernel<<<edgeBlocks, 256, 0, stream>>>(dst, deg);
    scanA_kernel<<<NB_SCAN, 256, 0, stream>>>(deg, locEx, blockSum);
    scanBC_kernel<<<NB_SCAN, 256, 0, stream>>>(locEx, blockSum, off);
    fill_kernel<<<edgeBlocks, 256, 0, stream>>>(src, dst, off, cursor, csr_src);

    // ---- 3 fused layers ----
    conv_fused<1><<<convBlocks, 256, 0, stream>>>(Xb,  off, csr_src, Wb + 0 * F * F, Wb + 1 * F * F, b1, H1b);
    conv_fused<1><<<convBlocks, 256, 0, stream>>>(H1b, off, csr_src, Wb + 2 * F * F, Wb + 3 * F * F, b2, H2b);
    conv_fused<0><<<convBlocks, 256, 0, stream>>>(H2b, off, csr_src, Wb + 4 * F * F, Wb + 5 * F * F, b3, H1b);

    // ---- pool + head ----
    pool_kernel<<<N_GRAPHS, 256, 0, stream>>>(H1b, batch, G);
    head_kernel<<<1, 640, 0, stream>>>(G, Wl, bl, out);
}